// Round 6
// baseline (365.878 us; speedup 1.0000x reference)
//
#include <hip/hip_runtime.h>
#include <hip/hip_bf16.h>
#include <stdint.h>

#define B_ROWS 16384
#define IN_DIM 2048
#define OUT_DIM 2048

typedef __attribute__((ext_vector_type(4))) float f32x4;
typedef __attribute__((ext_vector_type(8))) short s16x8;
typedef __attribute__((ext_vector_type(4))) unsigned short u16x4;

__device__ __forceinline__ unsigned short f2bf_rne(float f) {
  union { float f; unsigned u; } c; c.f = f;
  unsigned u = c.u;
  return (unsigned short)((u + 0x7FFFu + ((u >> 16) & 1u)) >> 16);
}

// Prep, rewritten for request-rate: all loads are CONTIGUOUS float4 (1 KB per
// wave-instruction, one request per 64B line) instead of the old 16B@32B-stride
// interleaved pairs (two half-line requests per line, 2x request count on the
// 144 MB read side).  Stores: 8B ushort4 per lane, contiguous 512B/instr.
// X: blocks [0,4096): one wave per row (bf16 cast + L2 norm, shuffle reduce).
// W: blocks [4096,6144): 2 contiguous float4 per thread.
#define PREP_X_BLOCKS 4096
#define PREP_W_BLOCKS 2048

__global__ void __launch_bounds__(256) prep_kernel(const float* __restrict__ x,
                                                   unsigned short* __restrict__ xn,
                                                   float* __restrict__ scale,
                                                   const float* __restrict__ W,
                                                   unsigned short* __restrict__ Wb) {
  if (blockIdx.x < PREP_X_BLOCKS) {
    const int row  = (blockIdx.x * 256 + threadIdx.x) >> 6;
    const int lane = threadIdx.x & 63;
    const f32x4* xr = (const f32x4*)(x + (size_t)row * IN_DIM);
    u16x4* xw = (u16x4*)(xn + (size_t)row * IN_DIM);

    float ss = 0.0f;
    #pragma unroll
    for (int j = 0; j < 8; ++j) {
      const int i = j * 64 + lane;          // contiguous float4 across lanes
      f32x4 v = xr[i];
      ss = fmaf(v[0], v[0], ss);
      ss = fmaf(v[1], v[1], ss);
      ss = fmaf(v[2], v[2], ss);
      ss = fmaf(v[3], v[3], ss);
      u16x4 p;
      p[0] = f2bf_rne(v[0]); p[1] = f2bf_rne(v[1]);
      p[2] = f2bf_rne(v[2]); p[3] = f2bf_rne(v[3]);
      xw[i] = p;                            // 8B/lane, contiguous 512B/instr
    }

    #pragma unroll
    for (int m = 32; m > 0; m >>= 1) ss += __shfl_xor(ss, m, 64);
    if (lane == 0) scale[row] = 1.0f / (sqrtf(ss) + 1e-4f);
  } else {
    const int base = (blockIdx.x - PREP_X_BLOCKS) * 512 + threadIdx.x;
    const f32x4* wr = (const f32x4*)W;
    u16x4* ww = (u16x4*)Wb;
    #pragma unroll
    for (int j = 0; j < 2; ++j) {
      const int i = base + j * 256;         // contiguous float4 across threads
      f32x4 v = wr[i];
      u16x4 p;
      p[0] = f2bf_rne(v[0]); p[1] = f2bf_rne(v[1]);
      p[2] = f2bf_rne(v[2]); p[3] = f2bf_rne(v[3]);
      ww[i] = p;
    }
  }
}

// ===========================================================================
// GEMM: exact revert to the Round-2 variant (best measured: 134.5 us median,
// MfmaUtil ~41%).  256x256 tile, BK=64, 512 threads (8 waves 2Mx4N), per-wave
// 128x64, acc[8][4].  4-phase pipelined: each phase issues the ds_reads for
// the NEXT phase's MFMA group, runs the CURRENT group's MFMA on regs loaded
// one phase ago.  A-frags ping-pong aP/aQ; bf[ni][kk] persists across tile.
//   p1: issue R2(T) | GLD A-even(T+1) | MFMA G1 | vmcnt(4) barrier
//   p2: issue R3(T) | GLD B-h1 (T+1) | MFMA G2
//   p3: issue R4(T) | GLD A-odd (T+1) | MFMA G3 | vmcnt(2) barrier
//   p4: issue R1(T+1) from buf nxt | GLD B-h0(T+2) -> buf[cur] | MFMA G4
// 2 barriers per K-tile (the two vmcnt fence points).  Ledger verified:
// end-p1 outstanding 6 -> vmcnt(4) waits A-odd(T); end-p3 outstanding 8 ->
// vmcnt(2) waits Bh0/Ae/Bh1(T+1).  Never vmcnt(0) in loop.  Dead prefetches
// at T=30/31 clamp to k=0.  XOR-8 chunk swizzle (0 bank conflicts).
// ===========================================================================

#define GLD16(SRC, DST)                                                        \
  __builtin_amdgcn_global_load_lds(                                            \
      (const __attribute__((address_space(1))) unsigned int*)(SRC),            \
      (__attribute__((address_space(3))) unsigned int*)(DST), 16, 0, 0)

__global__ void __launch_bounds__(512, 1) gemm_kernel(const unsigned short* __restrict__ A,
                                                      const unsigned short* __restrict__ Bm,
                                                      const float* __restrict__ scale,
                                                      const float* __restrict__ bias,
                                                      float* __restrict__ out) {
  __shared__ unsigned short As[2][256 * 64];
  __shared__ unsigned short Bs[2][256 * 64];

  const int tid = threadIdx.x;
  const int bid = blockIdx.x;
  // XCD swizzle: round-robin dispatch -> bid&7 is the XCD. Each XCD owns 8
  // consecutive bm (1MB A-slab in its L2) and sweeps all 8 bn.
  const int xcd = bid & 7;
  const int loc = bid >> 3;               // 0..63
  const int bm  = xcd * 8 + (loc >> 3);   // 0..63
  const int bn  = loc & 7;                // 0..7

  const int lane = tid & 63;
  const int wave = tid >> 6;              // 0..7
  const int wm   = wave >> 2;             // 0..1
  const int wn   = wave & 3;              // 0..3
  const int lrow = lane & 15;
  const int lq   = lane >> 4;

  // staging: thread t = row (t>>3), chunk (t&7) of a 64-row block;
  // LDS dest linear at byte t*16; global col pre-swizzled (XOR-8).
  const int sr = tid >> 3;
  const int sc = tid & 7;
  const unsigned short* aG = A  + (size_t)(bm * 256 + sr) * IN_DIM + ((sc ^ (sr & 7)) * 8);
  const unsigned short* bG = Bm + (size_t)(bn * 256 + sr) * IN_DIM + ((sc ^ (sr & 7)) * 8);

  // fragment read bases (element offsets into a 256x64 buffer)
  const int aRow = (wm * 128 + lrow) * 64;
  const int bRow = (wn * 64  + lrow) * 64;
  const int c0   = (lq ^ (lrow & 7)) * 8;   // kk=0 chunk; kk=1 chunk = c0^32

  f32x4 acc[8][4] = {};
  s16x8 aP[4], aQ[4];
  s16x8 bf[4][2];

  // --- prologue: stage tile 0 (B-h0,B-h1,A-even,A-odd) + B-h0(1)
  {
    char* aD = (char*)&As[0][0] + tid * 16;
    char* bD = (char*)&Bs[0][0] + tid * 16;
    char* bD1 = (char*)&Bs[1][0] + tid * 16;
    GLD16(bG,                         bD);           // B-h0(0)
    GLD16(bG + (size_t) 64 * IN_DIM,  bD + 8192);
    GLD16(bG + (size_t)128 * IN_DIM,  bD + 16384);   // B-h1(0)
    GLD16(bG + (size_t)192 * IN_DIM,  bD + 24576);
    GLD16(aG,                         aD);           // A-even(0): rows 0-63,128-191
    GLD16(aG + (size_t)128 * IN_DIM,  aD + 16384);
    GLD16(aG + (size_t) 64 * IN_DIM,  aD + 8192);    // A-odd(0): rows 64-127,192-255
    GLD16(aG + (size_t)192 * IN_DIM,  aD + 24576);
    GLD16(bG + 64,                        bD1);      // B-h0(1)
    GLD16(bG + 64 + (size_t)64 * IN_DIM,  bD1 + 8192);
  }
  asm volatile("s_waitcnt vmcnt(4)" ::: "memory");  // Bh0(0),Bh1(0),Ae(0) landed
  __builtin_amdgcn_s_barrier();

  // R1(0): aP <- A.msub0.kk0, bf[.][0] <- B.kk0  (buf0)
  #pragma unroll
  for (int mi = 0; mi < 4; ++mi)
    aP[mi] = *(const s16x8*)(&As[0][aRow + mi * 1024 + c0]);
  #pragma unroll
  for (int ni = 0; ni < 4; ++ni)
    bf[ni][0] = *(const s16x8*)(&Bs[0][bRow + ni * 1024 + c0]);

  for (int T = 0; T < IN_DIM / 64; ++T) {
    const int cur = T & 1, nxt = cur ^ 1;
    const unsigned short* Ac = &As[cur][0];
    const unsigned short* Bc = &Bs[cur][0];
    const unsigned short* An = &As[nxt][0];
    const unsigned short* Bn = &Bs[nxt][0];
    char* aD  = (char*)&As[nxt][0] + tid * 16;
    char* bD  = (char*)&Bs[nxt][0] + tid * 16;
    char* bDc = (char*)&Bs[cur][0] + tid * 16;     // B-h0(T+2) target = buf[cur]
    const size_t k1 = (size_t)((T < 31) ? (T + 1) * 64 : 0);  // dead at T=31
    const size_t k2 = (size_t)((T < 30) ? (T + 2) * 64 : 0);  // dead at T>=30

    // ---- p1: R2(T) | GLD A-even(T+1) | G1 | vmcnt(4) barrier
    #pragma unroll
    for (int mi = 0; mi < 4; ++mi)
      aQ[mi] = *(const s16x8*)(Ac + aRow + mi * 1024 + (c0 ^ 32));
    #pragma unroll
    for (int ni = 0; ni < 4; ++ni)
      bf[ni][1] = *(const s16x8*)(Bc + bRow + ni * 1024 + (c0 ^ 32));
    GLD16(aG + k1,                         aD);
    GLD16(aG + k1 + (size_t)128 * IN_DIM,  aD + 16384);
    __builtin_amdgcn_s_setprio(1);
    #pragma unroll
    for (int mi = 0; mi < 4; ++mi)
      #pragma unroll
      for (int ni = 0; ni < 4; ++ni)
        acc[mi][ni] = __builtin_amdgcn_mfma_f32_16x16x32_bf16(aP[mi], bf[ni][0], acc[mi][ni], 0, 0, 0);
    __builtin_amdgcn_s_setprio(0);
    asm volatile("s_waitcnt vmcnt(4)" ::: "memory");  // A-odd(T) landed
    __builtin_amdgcn_s_barrier();

    // ---- p2: R3(T) | GLD B-h1(T+1) | G2
    #pragma unroll
    for (int mi = 0; mi < 4; ++mi)
      aP[mi] = *(const s16x8*)(Ac + aRow + (4 + mi) * 1024 + c0);
    GLD16(bG + k1 + (size_t)128 * IN_DIM,  bD + 16384);
    GLD16(bG + k1 + (size_t)192 * IN_DIM,  bD + 24576);
    __builtin_amdgcn_s_setprio(1);
    #pragma unroll
    for (int mi = 0; mi < 4; ++mi)
      #pragma unroll
      for (int ni = 0; ni < 4; ++ni)
        acc[mi][ni] = __builtin_amdgcn_mfma_f32_16x16x32_bf16(aQ[mi], bf[ni][1], acc[mi][ni], 0, 0, 0);
    __builtin_amdgcn_s_setprio(0);

    // ---- p3: R4(T) | GLD A-odd(T+1) | G3 | vmcnt(2) barrier
    #pragma unroll
    for (int mi = 0; mi < 4; ++mi)
      aQ[mi] = *(const s16x8*)(Ac + aRow + (4 + mi) * 1024 + (c0 ^ 32));
    GLD16(aG + k1 + (size_t) 64 * IN_DIM,  aD + 8192);
    GLD16(aG + k1 + (size_t)192 * IN_DIM,  aD + 24576);
    __builtin_amdgcn_s_setprio(1);
    #pragma unroll
    for (int mi = 0; mi < 4; ++mi)
      #pragma unroll
      for (int ni = 0; ni < 4; ++ni)
        acc[4 + mi][ni] = __builtin_amdgcn_mfma_f32_16x16x32_bf16(aP[mi], bf[ni][0], acc[4 + mi][ni], 0, 0, 0);
    __builtin_amdgcn_s_setprio(0);
    asm volatile("s_waitcnt vmcnt(2)" ::: "memory");  // Bh0,Ae,Bh1(T+1) landed
    __builtin_amdgcn_s_barrier();

    // ---- p4: R1(T+1) from buf[nxt] | GLD B-h0(T+2) -> buf[cur] | G4
    #pragma unroll
    for (int mi = 0; mi < 4; ++mi)
      aP[mi] = *(const s16x8*)(An + aRow + mi * 1024 + c0);
    #pragma unroll
    for (int ni = 0; ni < 4; ++ni)
      bf[ni][0] = *(const s16x8*)(Bn + bRow + ni * 1024 + c0);
    GLD16(bG + k2,                         bDc);
    GLD16(bG + k2 + (size_t) 64 * IN_DIM,  bDc + 8192);
    __builtin_amdgcn_s_setprio(1);
    #pragma unroll
    for (int mi = 0; mi < 4; ++mi)
      #pragma unroll
      for (int ni = 0; ni < 4; ++ni)
        acc[4 + mi][ni] = __builtin_amdgcn_mfma_f32_16x16x32_bf16(aQ[mi], bf[ni][1], acc[4 + mi][ni], 0, 0, 0);
    __builtin_amdgcn_s_setprio(0);
  }

  // ---------- epilogue: D lane map col=lane&15, row=(lane>>4)*4 + r
  const int row0 = bm * 256 + wm * 128 + lq * 4;
  const int col0 = bn * 256 + wn * 64 + lrow;
  #pragma unroll
  for (int mi = 0; mi < 8; ++mi) {
    const int row = row0 + mi * 16;
    const f32x4 sc4 = *(const f32x4*)(scale + row);
    #pragma unroll
    for (int ni = 0; ni < 4; ++ni) {
      const int col = col0 + ni * 16;
      const float bcol = bias[col];
      #pragma unroll
      for (int r = 0; r < 4; ++r) {
        float v = acc[mi][ni][r] * sc4[r] + bcol;
        out[(size_t)(row + r) * OUT_DIM + col] = fmaxf(v, 0.0f);
      }
    }
  }
}

extern "C" void kernel_launch(void* const* d_in, const int* in_sizes, int n_in,
                              void* d_out, int out_size, void* d_ws, size_t ws_size,
                              hipStream_t stream) {
  const float* x = (const float*)d_in[0];
  const float* W = (const float*)d_in[1];
  const float* b = (const float*)d_in[2];
  float* out = (float*)d_out;

  char* ws = (char*)d_ws;
  unsigned short* xn    = (unsigned short*)ws;                                  // 67108864 B
  unsigned short* Wb    = (unsigned short*)(ws + (size_t)67108864);             //  8388608 B
  float*          scale = (float*)(ws + (size_t)67108864 + (size_t)8388608);    //    65536 B

  prep_kernel<<<PREP_X_BLOCKS + PREP_W_BLOCKS, 256, 0, stream>>>(x, xn, scale, W, Wb);

  gemm_kernel<<<(OUT_DIM / 256) * (B_ROWS / 256), 512, 0, stream>>>(xn, Wb, scale, b, out);
}